// Round 1
// baseline (852.759 us; speedup 1.0000x reference)
//
#include <hip/hip_runtime.h>
#include <hip/hip_bf16.h>

// Problem constants
#define B_    4
#define C_    64
#define MX_   32
#define MY_   32
#define MZ_   32
#define MVOX  32768      // 32*32*32
#define NATOM 64
#define EMB_  128
#define NHEAD 8
#define HEAD_ 8

// ---------------------------------------------------------------------------
// Kernel 1: K/V projections.  k = mol_embed @ Wk^T + bk  (layout [b][atom][c])
// grid (B, 2): blockIdx.y==0 -> K, ==1 -> V
// ---------------------------------------------------------------------------
__global__ __launch_bounds__(256) void kv_kernel(
    const float* __restrict__ mol,
    const float* __restrict__ Wk, const float* __restrict__ bk,
    const float* __restrict__ Wv, const float* __restrict__ bv,
    float* __restrict__ kout, float* __restrict__ vout) {
  __shared__ float smol[NATOM * EMB_];   // 32 KB
  __shared__ float sw[C_ * EMB_];        // 32 KB
  const int b = blockIdx.x;
  const bool is_v = (blockIdx.y == 1);
  const float* W    = is_v ? Wv : Wk;
  const float* bias = is_v ? bv : bk;
  float* out        = is_v ? vout : kout;

  for (int i = threadIdx.x; i < NATOM * EMB_; i += 256) {
    smol[i] = mol[b * NATOM * EMB_ + i];
    sw[i]   = W[i];
  }
  __syncthreads();

  for (int idx = threadIdx.x; idx < NATOM * C_; idx += 256) {
    const int a = idx >> 6, c = idx & 63;
    float acc = bias[c];
    #pragma unroll 8
    for (int e = 0; e < EMB_; ++e) acc += smol[a * EMB_ + e] * sw[c * EMB_ + e];
    out[b * NATOM * C_ + idx] = acc;
  }
}

// ---------------------------------------------------------------------------
// Kernel 2: fused Q-proj + ragged attention + O-proj + ReLU.
// One block = one batch, 64 consecutive voxels. grid (512, B), block 256.
// Writes o_mid in [b][c][voxel] layout (conv input layout).
// ---------------------------------------------------------------------------
__global__ __launch_bounds__(256) void attn_kernel(
    const float* __restrict__ x,
    const float* __restrict__ kbuf, const float* __restrict__ vbuf,
    const int* __restrict__ batch_nodes,
    const float* __restrict__ Wq, const float* __restrict__ bq,
    const float* __restrict__ Wo, const float* __restrict__ bo,
    float* __restrict__ omid) {
  __shared__ float xs[C_][65];     // x tile, [ci][vox]
  __shared__ float qs[64][65];     // q, [vox][c]
  __shared__ float os[64][65];     // attn out, [vox][c]
  __shared__ float swq[C_ * C_];   // Wq [co][ci]
  __shared__ float swo[C_ * C_];
  __shared__ float sk[NATOM * C_]; // K [a][c]
  __shared__ float sv[NATOM * C_];
  __shared__ float sbq[C_], sbo[C_];

  const int b   = blockIdx.y;
  const int m0  = blockIdx.x * 64;
  const int tid = threadIdx.x;
  const int vox = tid & 63;
  const int grp = tid >> 6;        // 0..3

  for (int c = grp; c < C_; c += 4)
    xs[c][vox] = x[(b * C_ + c) * MVOX + m0 + vox];
  for (int i = tid; i < C_ * C_; i += 256) {
    swq[i] = Wq[i];
    swo[i] = Wo[i];
    sk[i]  = kbuf[b * NATOM * C_ + i];
    sv[i]  = vbuf[b * NATOM * C_ + i];
  }
  if (tid < C_) { sbq[tid] = bq[tid]; sbo[tid] = bo[tid]; }
  __syncthreads();

  // ---- Q projection (pre-scaled by 1/sqrt(HEAD)) ----
  const float scale = 0.3535533905932738f;
  #pragma unroll 4
  for (int j = 0; j < 16; ++j) {
    const int co = grp * 16 + j;
    float acc = sbq[co];
    #pragma unroll 8
    for (int ci = 0; ci < C_; ++ci) acc += xs[ci][vox] * swq[co * C_ + ci];
    qs[vox][co] = acc * scale;
  }
  __syncthreads();

  // ---- attention: each thread does 2 heads for its voxel ----
  const int nv = batch_nodes[b];   // 1..64 valid atoms
  for (int hi = 0; hi < 2; ++hi) {
    const int h = grp * 2 + hi;
    float qreg[8];
    #pragma unroll
    for (int d = 0; d < 8; ++d) qreg[d] = qs[vox][h * 8 + d];
    float mrun = -1e30f, l = 0.f;
    float acc[8];
    #pragma unroll
    for (int d = 0; d < 8; ++d) acc[d] = 0.f;
    for (int a = 0; a < nv; ++a) {
      float logit = 0.f;
      #pragma unroll
      for (int d = 0; d < 8; ++d) logit += qreg[d] * sk[a * C_ + h * 8 + d];
      const float mn  = fmaxf(mrun, logit);
      const float cor = __expf(mrun - mn);
      const float p   = __expf(logit - mn);
      l = l * cor + p;
      #pragma unroll
      for (int d = 0; d < 8; ++d) acc[d] = acc[d] * cor + p * sv[a * C_ + h * 8 + d];
      mrun = mn;
    }
    const float inv = 1.f / l;
    #pragma unroll
    for (int d = 0; d < 8; ++d) os[vox][h * 8 + d] = acc[d] * inv;
  }
  __syncthreads();

  // ---- O projection + ReLU, store [b][co][voxel] ----
  #pragma unroll 4
  for (int j = 0; j < 16; ++j) {
    const int co = grp * 16 + j;
    float acc = sbo[co];
    #pragma unroll 8
    for (int ci = 0; ci < C_; ++ci) acc += os[vox][ci] * swo[co * C_ + ci];
    omid[(b * C_ + co) * MVOX + m0 + vox] = fmaxf(acc, 0.f);
  }
}

// ---------------------------------------------------------------------------
// Kernel 3: conv3d 3x3x3 circular + bias + ReLU + residual.
// grid (16 x-pairs, 8 y-quads, B). block 256 = 8 co_g x 4 y x 8 z_t.
// Per-thread: 2x * 4z * 8co = 64 accumulators (register blocked).
// ---------------------------------------------------------------------------
__global__ __launch_bounds__(256, 2) void conv_kernel(
    const float* __restrict__ in,    // o_mid [b][ci][x][y][z]
    const float* __restrict__ Wc,    // [co][ci][3][3][3]
    const float* __restrict__ bc,
    const float* __restrict__ xin,   // residual
    float* __restrict__ out) {
  __shared__ float xt[4][6][32];     // halo tile for one ci: 3 KB
  __shared__ float wt[C_ * 27];      // weights for one ci, [co][tap]: 6.9 KB

  const int b   = blockIdx.z;
  const int x0  = blockIdx.x * 2;
  const int y0  = blockIdx.y * 4;
  const int tid = threadIdx.x;
  const int z_t   = tid & 7;          // z0 = z_t*4
  const int y_loc = (tid >> 3) & 3;
  const int co_g  = tid >> 5;         // co0 = co_g*8
  const int z0  = z_t * 4;
  const int co0 = co_g * 8;

  float acc[2][4][8];
  #pragma unroll
  for (int xl = 0; xl < 2; ++xl)
    #pragma unroll
    for (int t = 0; t < 4; ++t)
      #pragma unroll
      for (int c = 0; c < 8; ++c) acc[xl][t][c] = 0.f;

  for (int ci = 0; ci < C_; ++ci) {
    __syncthreads();   // previous iteration's reads complete before restage
    // stage input halo tile: x in [x0-1,x0+2], y in [y0-1,y0+4], z full (wrap)
    for (int i = tid; i < 4 * 6 * 32; i += 256) {
      const int xi = i / 192;
      const int yi = (i / 32) % 6;
      const int zi = i & 31;
      const int gx = (x0 - 1 + xi) & 31;
      const int gy = (y0 - 1 + yi) & 31;
      xt[xi][yi][zi] = in[((b * C_ + ci) * MVOX) + gx * 1024 + gy * 32 + zi];
    }
    // stage weights for this ci: [co][tap]
    for (int i = tid; i < C_ * 27; i += 256) {
      const int co = i / 27, tap = i % 27;
      wt[i] = Wc[co * (C_ * 27) + ci * 27 + tap];
    }
    __syncthreads();

    #pragma unroll
    for (int dy = 0; dy < 3; ++dy) {
      const int yy = y_loc + dy;
      #pragma unroll
      for (int dx = 0; dx < 3; ++dx) {
        float w[3][8];
        #pragma unroll
        for (int dz = 0; dz < 3; ++dz)
          #pragma unroll
          for (int c = 0; c < 8; ++c)
            w[dz][c] = wt[(co0 + c) * 27 + dx * 9 + dy * 3 + dz];
        #pragma unroll
        for (int xl = 0; xl < 2; ++xl) {
          const int xa = xl + dx;   // input x-plane index in tile
          float zsp[6];
          #pragma unroll
          for (int jz = 0; jz < 6; ++jz)
            zsp[jz] = xt[xa][yy][(z0 + jz - 1) & 31];
          #pragma unroll
          for (int dz = 0; dz < 3; ++dz)
            #pragma unroll
            for (int t = 0; t < 4; ++t) {
              const float iv = zsp[t + dz];
              #pragma unroll
              for (int c = 0; c < 8; ++c)
                acc[xl][t][c] += iv * w[dz][c];
            }
        }
      }
    }
  }

  // epilogue: relu(acc + bias) + residual, float4 stores (z0 % 4 == 0)
  #pragma unroll
  for (int xl = 0; xl < 2; ++xl) {
    const int gx = x0 + xl;
    const int gy = y0 + y_loc;
    #pragma unroll
    for (int c = 0; c < 8; ++c) {
      const int co = co0 + c;
      const float bias = bc[co];
      const size_t base = ((size_t)(b * C_ + co)) * MVOX + gx * 1024 + gy * 32 + z0;
      const float4 xr = *reinterpret_cast<const float4*>(&xin[base]);
      float4 v;
      v.x = fmaxf(acc[xl][0][c] + bias, 0.f) + xr.x;
      v.y = fmaxf(acc[xl][1][c] + bias, 0.f) + xr.y;
      v.z = fmaxf(acc[xl][2][c] + bias, 0.f) + xr.z;
      v.w = fmaxf(acc[xl][3][c] + bias, 0.f) + xr.w;
      *reinterpret_cast<float4*>(&out[base]) = v;
    }
  }
}

// ---------------------------------------------------------------------------
extern "C" void kernel_launch(void* const* d_in, const int* in_sizes, int n_in,
                              void* d_out, int out_size, void* d_ws, size_t ws_size,
                              hipStream_t stream) {
  const float* x   = (const float*)d_in[0];
  const float* mol = (const float*)d_in[1];
  const int*   bn  = (const int*)  d_in[2];
  const float* Wq  = (const float*)d_in[3];
  const float* bq  = (const float*)d_in[4];
  const float* Wk  = (const float*)d_in[5];
  const float* bk  = (const float*)d_in[6];
  const float* Wv  = (const float*)d_in[7];
  const float* bv  = (const float*)d_in[8];
  const float* Wo  = (const float*)d_in[9];
  const float* bo  = (const float*)d_in[10];
  const float* Wc  = (const float*)d_in[11];
  const float* bc  = (const float*)d_in[12];
  float* out = (float*)d_out;

  char* ws = (char*)d_ws;
  float* omid = (float*)ws;                                   // 4*64*32768*4 = 33,554,432 B
  float* kbuf = (float*)(ws + (size_t)B_ * C_ * MVOX * 4);    // 4*64*64*4 = 65,536 B
  float* vbuf = (float*)(ws + (size_t)B_ * C_ * MVOX * 4 + (size_t)B_ * NATOM * C_ * 4);

  kv_kernel<<<dim3(B_, 2), 256, 0, stream>>>(mol, Wk, bk, Wv, bv, kbuf, vbuf);
  attn_kernel<<<dim3(MVOX / 64, B_), 256, 0, stream>>>(x, kbuf, vbuf, bn, Wq, bq, Wo, bo, omid);
  conv_kernel<<<dim3(MX_ / 2, MY_ / 4, B_), 256, 0, stream>>>(omid, Wc, bc, x, out);
}

// Round 2
// 529.972 us; speedup vs baseline: 1.6091x; 1.6091x over previous
//
#include <hip/hip_runtime.h>
#include <hip/hip_bf16.h>

#define B_    4
#define C_    64
#define MVOX  32768      // 32*32*32
#define NATOM 64
#define EMB_  128

typedef __attribute__((ext_vector_type(8))) __bf16 bf16x8;
typedef __attribute__((ext_vector_type(4))) float f32x4;
typedef __attribute__((ext_vector_type(8))) unsigned short ushort8;

// ---------------------------------------------------------------------------
// Kernel 0: weight prep  Wc[co][ci][3][3][3] f32 -> Wt[tap][co][ci] bf16
// ---------------------------------------------------------------------------
__global__ __launch_bounds__(256) void wprep_kernel(const float* __restrict__ Wc,
                                                    __hip_bfloat16* __restrict__ Wt) {
  const int i = blockIdx.x * 256 + threadIdx.x;
  if (i >= 27 * C_ * C_) return;
  const int tap = i >> 12;          // i / 4096
  const int rem = i & 4095;
  const int co = rem >> 6, ci = rem & 63;
  Wt[i] = __float2bfloat16(Wc[(co * C_ + ci) * 27 + tap]);
}

// ---------------------------------------------------------------------------
// Kernel 1: K/V projections (tiny)
// ---------------------------------------------------------------------------
__global__ __launch_bounds__(256) void kv_kernel(
    const float* __restrict__ mol,
    const float* __restrict__ Wk, const float* __restrict__ bk,
    const float* __restrict__ Wv, const float* __restrict__ bv,
    float* __restrict__ kout, float* __restrict__ vout) {
  __shared__ float smol[NATOM * EMB_];
  __shared__ float sw[C_ * EMB_];
  const int b = blockIdx.x;
  const bool is_v = (blockIdx.y == 1);
  const float* W    = is_v ? Wv : Wk;
  const float* bias = is_v ? bv : bk;
  float* out        = is_v ? vout : kout;

  for (int i = threadIdx.x; i < NATOM * EMB_; i += 256) {
    smol[i] = mol[b * NATOM * EMB_ + i];
    sw[i]   = W[i];
  }
  __syncthreads();
  for (int idx = threadIdx.x; idx < NATOM * C_; idx += 256) {
    const int a = idx >> 6, c = idx & 63;
    float acc = bias[c];
    #pragma unroll 8
    for (int e = 0; e < EMB_; ++e) acc += smol[a * EMB_ + e] * sw[c * EMB_ + e];
    out[b * NATOM * C_ + idx] = acc;
  }
}

// ---------------------------------------------------------------------------
// Kernel 2: fused Q-proj + ragged attention + O-proj + ReLU.
// Block = 64 voxels of one batch, 256 threads = (vox 0..63) x (grp 0..3).
// Thread (vox,grp) owns q/o channels [grp*16, grp*16+16) == heads 2grp,2grp+1.
// Output: o_mid bf16 channel-last [b][vox][ci].
// ---------------------------------------------------------------------------
__global__ __launch_bounds__(256) void attn_kernel(
    const float* __restrict__ x,
    const float* __restrict__ kbuf, const float* __restrict__ vbuf,
    const int* __restrict__ batch_nodes,
    const float* __restrict__ Wq, const float* __restrict__ bq,
    const float* __restrict__ Wo, const float* __restrict__ bo,
    __hip_bfloat16* __restrict__ omid) {
  __shared__ float xs[64][68];     // x tile, [vox][ci] padded (68%32=4 -> conflict-free b128)
  __shared__ float os[64][68];     // attn out
  __shared__ float swq[C_ * C_];   // [co][ci]
  __shared__ float swo[C_ * C_];
  __shared__ float sk[NATOM * C_]; // [a][c]
  __shared__ float sv[NATOM * C_];
  __shared__ float sbq[C_], sbo[C_];

  const int b   = blockIdx.y;
  const int m0  = blockIdx.x * 64;
  const int tid = threadIdx.x;
  const int vox = tid & 63;
  const int grp = tid >> 6;

  for (int c = grp; c < C_; c += 4)
    xs[vox][c] = x[(b * C_ + c) * MVOX + m0 + vox];
  for (int i = tid; i < C_ * C_; i += 256) {
    swq[i] = Wq[i]; swo[i] = Wo[i];
    sk[i]  = kbuf[b * NATOM * C_ + i];
    sv[i]  = vbuf[b * NATOM * C_ + i];
  }
  if (tid < C_) { sbq[tid] = bq[tid]; sbo[tid] = bo[tid]; }
  __syncthreads();

  // ---- Q projection into registers (co = grp*16+j), pre-scaled ----
  float qa[16];
  #pragma unroll
  for (int j = 0; j < 16; ++j) qa[j] = sbq[grp * 16 + j];
  for (int c4 = 0; c4 < 16; ++c4) {
    const f32x4 xv = *(const f32x4*)&xs[vox][c4 * 4];
    #pragma unroll
    for (int j = 0; j < 16; ++j) {
      const f32x4 wv = *(const f32x4*)&swq[(grp * 16 + j) * C_ + c4 * 4];  // uniform broadcast
      qa[j] += xv.x * wv.x + xv.y * wv.y + xv.z * wv.z + xv.w * wv.w;
    }
  }
  const float scale = 0.3535533905932738f;
  #pragma unroll
  for (int j = 0; j < 16; ++j) qa[j] *= scale;

  // ---- ragged online-softmax attention: 2 heads per thread ----
  const int nv = batch_nodes[b];   // 1..64
  float ores[16];
  #pragma unroll
  for (int hi = 0; hi < 2; ++hi) {
    const int h = grp * 2 + hi;
    float mrun = -1e30f, l = 0.f;
    float acc[8];
    #pragma unroll
    for (int d = 0; d < 8; ++d) acc[d] = 0.f;
    for (int a = 0; a < nv; ++a) {
      const f32x4 k0 = *(const f32x4*)&sk[a * C_ + h * 8];      // uniform broadcast
      const f32x4 k1 = *(const f32x4*)&sk[a * C_ + h * 8 + 4];
      float logit = qa[hi*8+0]*k0.x + qa[hi*8+1]*k0.y + qa[hi*8+2]*k0.z + qa[hi*8+3]*k0.w
                  + qa[hi*8+4]*k1.x + qa[hi*8+5]*k1.y + qa[hi*8+6]*k1.z + qa[hi*8+7]*k1.w;
      const float mn  = fmaxf(mrun, logit);
      const float cor = __expf(mrun - mn);
      const float p   = __expf(logit - mn);
      l = l * cor + p;
      const f32x4 v0 = *(const f32x4*)&sv[a * C_ + h * 8];
      const f32x4 v1 = *(const f32x4*)&sv[a * C_ + h * 8 + 4];
      acc[0] = acc[0] * cor + p * v0.x;  acc[1] = acc[1] * cor + p * v0.y;
      acc[2] = acc[2] * cor + p * v0.z;  acc[3] = acc[3] * cor + p * v0.w;
      acc[4] = acc[4] * cor + p * v1.x;  acc[5] = acc[5] * cor + p * v1.y;
      acc[6] = acc[6] * cor + p * v1.z;  acc[7] = acc[7] * cor + p * v1.w;
      mrun = mn;
    }
    const float inv = 1.f / l;
    #pragma unroll
    for (int d = 0; d < 8; ++d) ores[hi * 8 + d] = acc[d] * inv;
  }
  #pragma unroll
  for (int j = 0; j < 16; ++j) os[vox][grp * 16 + j] = ores[j];
  __syncthreads();

  // ---- O projection + ReLU -> bf16 channel-last store ----
  float oa[16];
  #pragma unroll
  for (int j = 0; j < 16; ++j) oa[j] = sbo[grp * 16 + j];
  for (int c4 = 0; c4 < 16; ++c4) {
    const f32x4 ov = *(const f32x4*)&os[vox][c4 * 4];
    #pragma unroll
    for (int j = 0; j < 16; ++j) {
      const f32x4 wv = *(const f32x4*)&swo[(grp * 16 + j) * C_ + c4 * 4];  // uniform broadcast
      oa[j] += ov.x * wv.x + ov.y * wv.y + ov.z * wv.z + ov.w * wv.w;
    }
  }
  ushort8 p0, p1;
  #pragma unroll
  for (int j = 0; j < 8; ++j) {
    __hip_bfloat16 h0 = __float2bfloat16(fmaxf(oa[j], 0.f));
    __hip_bfloat16 h1 = __float2bfloat16(fmaxf(oa[j + 8], 0.f));
    p0[j] = *(unsigned short*)&h0;
    p1[j] = *(unsigned short*)&h1;
  }
  __hip_bfloat16* dst = omid + ((size_t)(b * MVOX + m0 + vox) * C_ + grp * 16);
  *(ushort8*)dst = p0;
  *(ushort8*)(dst + 8) = p1;
}

// ---------------------------------------------------------------------------
// Kernel 3: conv3d 3x3x3 circular via implicit-GEMM MFMA (bf16 in, f32 acc).
//   in : o_mid bf16 [b][vox][ci]  (vox = x*1024+y*32+z, 128B rows)
//   Wt : bf16 [tap][co][ci], tap = dx*9+dy*3+dz
// Block: 2x2 (x,y) lines x 32 z = 128 out voxels, all 64 co. 4 waves, wave w
// owns line (xl=w>>1, yl=w&1). Halo 4x4 lines staged once in LDS, XOR-swizzled
// (16B col ^= z&7) so ds_read_b128 of 16 z-consecutive rows is conflict-free.
// MFMA: A = Wt rows (M=co), B = voxel rows (N=vox), D[co][vox].
// ---------------------------------------------------------------------------
__global__ __launch_bounds__(256, 2) void conv_kernel(
    const __hip_bfloat16* __restrict__ omid,
    const __hip_bfloat16* __restrict__ Wt,
    const float* __restrict__ bc,
    const float* __restrict__ xin,
    float* __restrict__ out) {
  __shared__ __hip_bfloat16 halo[512 * 64];   // 64 KB: rows = (xi*4+yi)*32+z

  const int b    = blockIdx.y;
  const int x0   = (blockIdx.x >> 4) * 2;
  const int y0   = (blockIdx.x & 15) * 2;
  const int tid  = threadIdx.x;
  const int lane = tid & 63;
  const int w    = tid >> 6;

  // --- stage halo: each wave 16 chunks of 8 rows (1 KB), reg-staged swizzle ---
  const __hip_bfloat16* src = omid + (size_t)b * MVOX * C_;
  uint4 tmp[16];
  #pragma unroll
  for (int n = 0; n < 16; ++n) {
    const int chunk = w * 16 + n;            // 0..63
    const int li = chunk >> 2;               // halo line 0..15
    const int z  = (chunk & 3) * 8 + (lane >> 3);
    const int gx = (x0 - 1 + (li >> 2)) & 31;
    const int gy = (y0 - 1 + (li & 3)) & 31;
    tmp[n] = *(const uint4*)(src + ((size_t)(gx * 1024 + gy * 32 + z) * C_ + (lane & 7) * 8));
  }
  #pragma unroll
  for (int n = 0; n < 16; ++n) {
    const int chunk = w * 16 + n;
    const int zl = lane >> 3;                // z&7 (chunks are 8-row aligned)
    const int d16 = chunk * 64 + zl * 8 + ((lane & 7) ^ zl);
    *(uint4*)&halo[d16 * 8] = tmp[n];
  }
  __syncthreads();

  const int xl = w >> 1, yl = w & 1;
  const int row = lane & 15, quad = lane >> 4;

  f32x4 acc[4][2];
  #pragma unroll
  for (int cf = 0; cf < 4; ++cf)
    #pragma unroll
    for (int f = 0; f < 2; ++f)
      #pragma unroll
      for (int r = 0; r < 4; ++r) acc[cf][f][r] = 0.f;

  for (int dxy = 0; dxy < 9; ++dxy) {
    const int dx = dxy / 3, dy = dxy - dx * 3;
    const int hline = (xl + dx) * 4 + (yl + dy);      // halo line index
    #pragma unroll
    for (int dz = 0; dz < 3; ++dz) {
      const __hip_bfloat16* Wtap = Wt + (dxy * 3 + dz) * 4096;
      bf16x8 bfr[2][2];
      #pragma unroll
      for (int f = 0; f < 2; ++f) {
        const int zs = (f * 16 + row + dz - 1) & 31;
        const int sw = zs & 7;
        #pragma unroll
        for (int kh = 0; kh < 2; ++kh) {
          const int a16 = (hline * 32 + zs) * 8 + ((kh * 4 + quad) ^ sw);
          bfr[f][kh] = *(const bf16x8*)&halo[a16 * 8];
        }
      }
      #pragma unroll
      for (int kh = 0; kh < 2; ++kh) {
        #pragma unroll
        for (int cf = 0; cf < 4; ++cf) {
          const bf16x8 afr = *(const bf16x8*)(Wtap + ((cf * 16 + row) * C_ + kh * 32 + quad * 8));
          acc[cf][0] = __builtin_amdgcn_mfma_f32_16x16x32_bf16(afr, bfr[0][kh], acc[cf][0], 0, 0, 0);
          acc[cf][1] = __builtin_amdgcn_mfma_f32_16x16x32_bf16(afr, bfr[1][kh], acc[cf][1], 0, 0, 0);
        }
      }
    }
  }

  // --- epilogue: relu(acc+bias) + residual, f32 [b][co][vox] ---
  const int gx = x0 + xl, gy = y0 + yl;
  #pragma unroll
  for (int cf = 0; cf < 4; ++cf)
    #pragma unroll
    for (int f = 0; f < 2; ++f) {
      const int z = f * 16 + row;
      #pragma unroll
      for (int r = 0; r < 4; ++r) {
        const int co = cf * 16 + quad * 4 + r;
        const size_t idx = ((size_t)(b * C_ + co)) * MVOX + gx * 1024 + gy * 32 + z;
        out[idx] = fmaxf(acc[cf][f][r] + bc[co], 0.f) + xin[idx];
      }
    }
}

// ---------------------------------------------------------------------------
extern "C" void kernel_launch(void* const* d_in, const int* in_sizes, int n_in,
                              void* d_out, int out_size, void* d_ws, size_t ws_size,
                              hipStream_t stream) {
  const float* x   = (const float*)d_in[0];
  const float* mol = (const float*)d_in[1];
  const int*   bn  = (const int*)  d_in[2];
  const float* Wq  = (const float*)d_in[3];
  const float* bq  = (const float*)d_in[4];
  const float* Wk  = (const float*)d_in[5];
  const float* bk  = (const float*)d_in[6];
  const float* Wv  = (const float*)d_in[7];
  const float* bv  = (const float*)d_in[8];
  const float* Wo  = (const float*)d_in[9];
  const float* bo  = (const float*)d_in[10];
  const float* Wc  = (const float*)d_in[11];
  const float* bc  = (const float*)d_in[12];
  float* out = (float*)d_out;

  char* ws = (char*)d_ws;
  __hip_bfloat16* omid = (__hip_bfloat16*)ws;                        // 16,777,216 B
  float* kbuf = (float*)(ws + 16777216);                             // 65,536 B
  float* vbuf = kbuf + B_ * NATOM * C_;                              // 65,536 B
  __hip_bfloat16* Wt = (__hip_bfloat16*)(ws + 16777216 + 2 * 65536); // 221,184 B

  wprep_kernel<<<dim3((27 * C_ * C_ + 255) / 256), 256, 0, stream>>>(Wc, Wt);
  kv_kernel<<<dim3(B_, 2), 256, 0, stream>>>(mol, Wk, bk, Wv, bv, kbuf, vbuf);
  attn_kernel<<<dim3(MVOX / 64, B_), 256, 0, stream>>>(x, kbuf, vbuf, bn, Wq, bq, Wo, bo, omid);
  conv_kernel<<<dim3(256, B_), 256, 0, stream>>>(omid, Wt, bc, x, out);
}

// Round 3
// 273.604 us; speedup vs baseline: 3.1168x; 1.9370x over previous
//
#include <hip/hip_runtime.h>
#include <hip/hip_bf16.h>

#define B_    4
#define C_    64
#define MVOX  32768      // 32*32*32
#define NATOM 64
#define EMB_  128

typedef __attribute__((ext_vector_type(8))) __bf16 bf16x8;
typedef __attribute__((ext_vector_type(4))) float f32x4;
typedef __attribute__((ext_vector_type(8))) unsigned short ushort8;

// ---------------------------------------------------------------------------
// Kernel 0: weight prep  Wc[co][ci][3][3][3] f32 -> Wt[tap][co][ci] bf16
// ---------------------------------------------------------------------------
__global__ __launch_bounds__(256) void wprep_kernel(const float* __restrict__ Wc,
                                                    __hip_bfloat16* __restrict__ Wt) {
  const int i = blockIdx.x * 256 + threadIdx.x;
  if (i >= 27 * C_ * C_) return;
  const int tap = i >> 12;
  const int rem = i & 4095;
  const int co = rem >> 6, ci = rem & 63;
  Wt[i] = __float2bfloat16(Wc[(co * C_ + ci) * 27 + tap]);
}

// ---------------------------------------------------------------------------
// Kernel 1: K/V projections (tiny)
// ---------------------------------------------------------------------------
__global__ __launch_bounds__(256) void kv_kernel(
    const float* __restrict__ mol,
    const float* __restrict__ Wk, const float* __restrict__ bk,
    const float* __restrict__ Wv, const float* __restrict__ bv,
    float* __restrict__ kout, float* __restrict__ vout) {
  __shared__ float smol[NATOM * EMB_];
  __shared__ float sw[C_ * EMB_];
  const int b = blockIdx.x;
  const bool is_v = (blockIdx.y == 1);
  const float* W    = is_v ? Wv : Wk;
  const float* bias = is_v ? bv : bk;
  float* out        = is_v ? vout : kout;

  for (int i = threadIdx.x; i < NATOM * EMB_; i += 256) {
    smol[i] = mol[b * NATOM * EMB_ + i];
    sw[i]   = W[i];
  }
  __syncthreads();
  for (int idx = threadIdx.x; idx < NATOM * C_; idx += 256) {
    const int a = idx >> 6, c = idx & 63;
    float acc = bias[c];
    #pragma unroll 8
    for (int e = 0; e < EMB_; ++e) acc += smol[a * EMB_ + e] * sw[c * EMB_ + e];
    out[b * NATOM * C_ + idx] = acc;
  }
}

// ---------------------------------------------------------------------------
// Kernel 2: fused Q-proj + ragged attention + O-proj + ReLU.
// 512 threads = 64 vox x 8 heads (1 head per thread; h wave-uniform).
// Logits for 64 atoms live in registers (two 32-atom chunks, static unroll)
// -> independent exps, no serial softmax chain. Weights read via scalar
// cache (wave-uniform addresses); x read coalesced from global (L1 absorbs
// the 8x head redundancy). LDS: K/V (32 KB) + one 16 KB exchange buffer.
// Output: o_mid bf16 channel-last [b][vox][ci], coalesced 128B-row stores.
// ---------------------------------------------------------------------------
__global__ __launch_bounds__(512, 4) void attn_kernel(
    const float* __restrict__ x,
    const float* __restrict__ kbuf, const float* __restrict__ vbuf,
    const int* __restrict__ batch_nodes,
    const float* __restrict__ Wq, const float* __restrict__ bq,
    const float* __restrict__ Wo, const float* __restrict__ bo,
    __hip_bfloat16* __restrict__ omid) {
  __shared__ float sk[NATOM * C_];   // 16 KB
  __shared__ float sv[NATOM * C_];   // 16 KB
  __shared__ float os[64 * C_];      // 16 KB exchange (f32, then bf16 alias)

  const int b   = blockIdx.y;
  const int m0  = blockIdx.x * 64;
  const int tid = threadIdx.x;
  const int vox = tid & 63;
  const int h   = __builtin_amdgcn_readfirstlane(tid >> 6);  // wave-uniform head

  // stage K/V (completes under Q-proj; barrier below)
  for (int i = tid; i < NATOM * C_; i += 512) {
    sk[i] = kbuf[b * NATOM * C_ + i];
    sv[i] = vbuf[b * NATOM * C_ + i];
  }

  // ---- Q projection: thread computes q[8] for (vox, head h) ----
  float qa[8];
  #pragma unroll
  for (int j = 0; j < 8; ++j) qa[j] = bq[h * 8 + j];
  #pragma unroll 4
  for (int c4 = 0; c4 < 16; ++c4) {
    float xv[4];
    #pragma unroll
    for (int r = 0; r < 4; ++r)
      xv[r] = x[(size_t)(b * C_ + c4 * 4 + r) * MVOX + m0 + vox];
    #pragma unroll
    for (int j = 0; j < 8; ++j) {
      const f32x4 wv = *(const f32x4*)&Wq[(h * 8 + j) * C_ + c4 * 4];  // scalar-cache
      qa[j] += xv[0] * wv.x + xv[1] * wv.y + xv[2] * wv.z + xv[3] * wv.w;
    }
  }
  const float scale = 0.3535533905932738f;
  #pragma unroll
  for (int j = 0; j < 8; ++j) qa[j] *= scale;

  __syncthreads();   // K/V staged

  // ---- ragged attention, two 32-atom chunks, logits in registers ----
  const int nv = batch_nodes[b];   // 1..64
  float mrun = -1e30f, lsum = 0.f;
  float acc[8];
  #pragma unroll
  for (int d = 0; d < 8; ++d) acc[d] = 0.f;

  #pragma unroll
  for (int ch = 0; ch < 2; ++ch) {
    float l[32];
    float cmax = -1e30f;
    #pragma unroll
    for (int a = 0; a < 32; ++a) {
      const int atom = ch * 32 + a;
      const f32x4 k0 = *(const f32x4*)&sk[atom * C_ + h * 8];      // LDS broadcast
      const f32x4 k1 = *(const f32x4*)&sk[atom * C_ + h * 8 + 4];
      float lg = qa[0]*k0.x + qa[1]*k0.y + qa[2]*k0.z + qa[3]*k0.w
               + qa[4]*k1.x + qa[5]*k1.y + qa[6]*k1.z + qa[7]*k1.w;
      lg = (atom < nv) ? lg : -1e30f;
      l[a] = lg;
      cmax = fmaxf(cmax, lg);
    }
    const float mnew = fmaxf(mrun, cmax);
    const float corr = __expf(mrun - mnew);   // 0 on first chunk
    lsum *= corr;
    #pragma unroll
    for (int d = 0; d < 8; ++d) acc[d] *= corr;
    #pragma unroll
    for (int a = 0; a < 32; ++a) {
      const int atom = ch * 32 + a;
      const float p = __expf(l[a] - mnew);    // independent exps
      lsum += p;
      const f32x4 v0 = *(const f32x4*)&sv[atom * C_ + h * 8];
      const f32x4 v1 = *(const f32x4*)&sv[atom * C_ + h * 8 + 4];
      acc[0] += p * v0.x;  acc[1] += p * v0.y;
      acc[2] += p * v0.z;  acc[3] += p * v0.w;
      acc[4] += p * v1.x;  acc[5] += p * v1.y;
      acc[6] += p * v1.z;  acc[7] += p * v1.w;
    }
    mrun = mnew;
  }
  const float inv = 1.f / lsum;

  // ---- write attention out to os (f32, XOR-swizzled cols) ----
  #pragma unroll
  for (int i = 0; i < 2; ++i) {
    const int c4 = h * 2 + i;
    f32x4 val;
    val.x = acc[i * 4 + 0] * inv; val.y = acc[i * 4 + 1] * inv;
    val.z = acc[i * 4 + 2] * inv; val.w = acc[i * 4 + 3] * inv;
    *(f32x4*)&os[vox * C_ + ((c4 ^ (vox & 15)) << 2)] = val;
  }
  __syncthreads();

  // ---- O projection + ReLU ----
  float oa[8];
  #pragma unroll
  for (int j = 0; j < 8; ++j) oa[j] = bo[h * 8 + j];
  #pragma unroll 4
  for (int c4 = 0; c4 < 16; ++c4) {
    const f32x4 ov = *(const f32x4*)&os[vox * C_ + ((c4 ^ (vox & 15)) << 2)];
    #pragma unroll
    for (int j = 0; j < 8; ++j) {
      const f32x4 wv = *(const f32x4*)&Wo[(h * 8 + j) * C_ + c4 * 4];  // scalar-cache
      oa[j] += ov.x * wv.x + ov.y * wv.y + ov.z * wv.z + ov.w * wv.w;
    }
  }
  __syncthreads();   // all os reads done before alias-overwrite

  // ---- pack bf16 into os alias (swizzled 16B chunks) ----
  __hip_bfloat16* osb = (__hip_bfloat16*)os;
  ushort8 pk;
  #pragma unroll
  for (int j = 0; j < 8; ++j) {
    __hip_bfloat16 hb = __float2bfloat16(fmaxf(oa[j], 0.f));
    pk[j] = *(unsigned short*)&hb;
  }
  *(ushort8*)&osb[vox * C_ + ((h ^ (vox & 7)) << 3)] = pk;
  __syncthreads();

  // ---- coalesced channel-last store: 128B per voxel row ----
  {
    const int v2 = tid >> 3, part = tid & 7;
    const ushort8 val = *(const ushort8*)&osb[v2 * C_ + ((part ^ (v2 & 7)) << 3)];
    *(ushort8*)(omid + (size_t)(b * MVOX + m0 + v2) * C_ + part * 8) = val;
  }
}

// ---------------------------------------------------------------------------
// Kernel 3: conv3d 3x3x3 circular via implicit-GEMM MFMA (bf16 in, f32 acc).
// (unchanged from R1)
// ---------------------------------------------------------------------------
__global__ __launch_bounds__(256, 2) void conv_kernel(
    const __hip_bfloat16* __restrict__ omid,
    const __hip_bfloat16* __restrict__ Wt,
    const float* __restrict__ bc,
    const float* __restrict__ xin,
    float* __restrict__ out) {
  __shared__ __hip_bfloat16 halo[512 * 64];   // 64 KB

  const int b    = blockIdx.y;
  const int x0   = (blockIdx.x >> 4) * 2;
  const int y0   = (blockIdx.x & 15) * 2;
  const int tid  = threadIdx.x;
  const int lane = tid & 63;
  const int w    = tid >> 6;

  const __hip_bfloat16* src = omid + (size_t)b * MVOX * C_;
  uint4 tmp[16];
  #pragma unroll
  for (int n = 0; n < 16; ++n) {
    const int chunk = w * 16 + n;
    const int li = chunk >> 2;
    const int z  = (chunk & 3) * 8 + (lane >> 3);
    const int gx = (x0 - 1 + (li >> 2)) & 31;
    const int gy = (y0 - 1 + (li & 3)) & 31;
    tmp[n] = *(const uint4*)(src + ((size_t)(gx * 1024 + gy * 32 + z) * C_ + (lane & 7) * 8));
  }
  #pragma unroll
  for (int n = 0; n < 16; ++n) {
    const int chunk = w * 16 + n;
    const int zl = lane >> 3;
    const int d16 = chunk * 64 + zl * 8 + ((lane & 7) ^ zl);
    *(uint4*)&halo[d16 * 8] = tmp[n];
  }
  __syncthreads();

  const int xl = w >> 1, yl = w & 1;
  const int row = lane & 15, quad = lane >> 4;

  f32x4 acc[4][2];
  #pragma unroll
  for (int cf = 0; cf < 4; ++cf)
    #pragma unroll
    for (int f = 0; f < 2; ++f)
      #pragma unroll
      for (int r = 0; r < 4; ++r) acc[cf][f][r] = 0.f;

  for (int dxy = 0; dxy < 9; ++dxy) {
    const int dx = dxy / 3, dy = dxy - dx * 3;
    const int hline = (xl + dx) * 4 + (yl + dy);
    #pragma unroll
    for (int dz = 0; dz < 3; ++dz) {
      const __hip_bfloat16* Wtap = Wt + (dxy * 3 + dz) * 4096;
      bf16x8 bfr[2][2];
      #pragma unroll
      for (int f = 0; f < 2; ++f) {
        const int zs = (f * 16 + row + dz - 1) & 31;
        const int sw = zs & 7;
        #pragma unroll
        for (int kh = 0; kh < 2; ++kh) {
          const int a16 = (hline * 32 + zs) * 8 + ((kh * 4 + quad) ^ sw);
          bfr[f][kh] = *(const bf16x8*)&halo[a16 * 8];
        }
      }
      #pragma unroll
      for (int kh = 0; kh < 2; ++kh) {
        #pragma unroll
        for (int cf = 0; cf < 4; ++cf) {
          const bf16x8 afr = *(const bf16x8*)(Wtap + ((cf * 16 + row) * C_ + kh * 32 + quad * 8));
          acc[cf][0] = __builtin_amdgcn_mfma_f32_16x16x32_bf16(afr, bfr[0][kh], acc[cf][0], 0, 0, 0);
          acc[cf][1] = __builtin_amdgcn_mfma_f32_16x16x32_bf16(afr, bfr[1][kh], acc[cf][1], 0, 0, 0);
        }
      }
    }
  }

  const int gx = x0 + xl, gy = y0 + yl;
  #pragma unroll
  for (int cf = 0; cf < 4; ++cf)
    #pragma unroll
    for (int f = 0; f < 2; ++f) {
      const int z = f * 16 + row;
      #pragma unroll
      for (int r = 0; r < 4; ++r) {
        const int co = cf * 16 + quad * 4 + r;
        const size_t idx = ((size_t)(b * C_ + co)) * MVOX + gx * 1024 + gy * 32 + z;
        out[idx] = fmaxf(acc[cf][f][r] + bc[co], 0.f) + xin[idx];
      }
    }
}

// ---------------------------------------------------------------------------
extern "C" void kernel_launch(void* const* d_in, const int* in_sizes, int n_in,
                              void* d_out, int out_size, void* d_ws, size_t ws_size,
                              hipStream_t stream) {
  const float* x   = (const float*)d_in[0];
  const float* mol = (const float*)d_in[1];
  const int*   bn  = (const int*)  d_in[2];
  const float* Wq  = (const float*)d_in[3];
  const float* bq  = (const float*)d_in[4];
  const float* Wk  = (const float*)d_in[5];
  const float* bk  = (const float*)d_in[6];
  const float* Wv  = (const float*)d_in[7];
  const float* bv  = (const float*)d_in[8];
  const float* Wo  = (const float*)d_in[9];
  const float* bo  = (const float*)d_in[10];
  const float* Wc  = (const float*)d_in[11];
  const float* bc  = (const float*)d_in[12];
  float* out = (float*)d_out;

  char* ws = (char*)d_ws;
  __hip_bfloat16* omid = (__hip_bfloat16*)ws;                        // 16,777,216 B
  float* kbuf = (float*)(ws + 16777216);
  float* vbuf = kbuf + B_ * NATOM * C_;
  __hip_bfloat16* Wt = (__hip_bfloat16*)(ws + 16777216 + 2 * 65536);

  wprep_kernel<<<dim3((27 * C_ * C_ + 255) / 256), 256, 0, stream>>>(Wc, Wt);
  kv_kernel<<<dim3(B_, 2), 256, 0, stream>>>(mol, Wk, bk, Wv, bv, kbuf, vbuf);
  attn_kernel<<<dim3(MVOX / 64, B_), 512, 0, stream>>>(x, kbuf, vbuf, bn, Wq, bq, Wo, bo, omid);
  conv_kernel<<<dim3(256, B_), 256, 0, stream>>>(omid, Wt, bc, x, out);
}

// Round 5
// 206.362 us; speedup vs baseline: 4.1324x; 1.3258x over previous
//
#include <hip/hip_runtime.h>
#include <hip/hip_bf16.h>

#define B_    4
#define C_    64
#define MVOX  32768      // 32*32*32
#define NATOM 64
#define EMB_  128

typedef __attribute__((ext_vector_type(8))) __bf16 bf16x8;
typedef __attribute__((ext_vector_type(4))) float f32x4;
typedef __attribute__((ext_vector_type(8))) unsigned short ushort8;

typedef __attribute__((address_space(1))) const unsigned int gas_u32;
typedef __attribute__((address_space(3))) unsigned int las_u32;

// ---------------------------------------------------------------------------
// Kernel 0: weight prep. Wc[co][ci][3][3][3] f32 -> Wt bf16, layout
// Wt[tap][co][c7][e] where logical 16B-chunk c = c7 ^ (co&7)  (pre-swizzled so
// linear global_load_lds staging yields conflict-free ds_read_b128 A-frags).
// ---------------------------------------------------------------------------
__global__ __launch_bounds__(256) void wprep_kernel(const float* __restrict__ Wc,
                                                    __hip_bfloat16* __restrict__ Wt) {
  const int i = blockIdx.x * 256 + threadIdx.x;
  if (i >= 27 * C_ * C_) return;
  const int tap = i >> 12;
  const int co  = (i >> 6) & 63;
  const int c7  = (i >> 3) & 7;
  const int e   = i & 7;
  const int ci  = ((c7 ^ (co & 7)) << 3) + e;
  Wt[i] = __float2bfloat16(Wc[(co * C_ + ci) * 27 + tap]);
}

// ---------------------------------------------------------------------------
// Kernel 1: K/V projections (tiny)
// ---------------------------------------------------------------------------
__global__ __launch_bounds__(256) void kv_kernel(
    const float* __restrict__ mol,
    const float* __restrict__ Wk, const float* __restrict__ bk,
    const float* __restrict__ Wv, const float* __restrict__ bv,
    float* __restrict__ kout, float* __restrict__ vout) {
  __shared__ float smol[NATOM * EMB_];
  __shared__ float sw[C_ * EMB_];
  const int b = blockIdx.x;
  const bool is_v = (blockIdx.y == 1);
  const float* W    = is_v ? Wv : Wk;
  const float* bias = is_v ? bv : bk;
  float* out        = is_v ? vout : kout;

  for (int i = threadIdx.x; i < NATOM * EMB_; i += 256) {
    smol[i] = mol[b * NATOM * EMB_ + i];
    sw[i]   = W[i];
  }
  __syncthreads();
  for (int idx = threadIdx.x; idx < NATOM * C_; idx += 256) {
    const int a = idx >> 6, c = idx & 63;
    float acc = bias[c];
    #pragma unroll 8
    for (int e = 0; e < EMB_; ++e) acc += smol[a * EMB_ + e] * sw[c * EMB_ + e];
    out[b * NATOM * C_ + idx] = acc;
  }
}

// ---------------------------------------------------------------------------
// Kernel 2: fused Q-proj + ragged attention + O-proj + ReLU.
// 512 threads = 64 vox x 8 heads. x tile staged to LDS via global_load_lds
// (xos, aliased with the os exchange buffer). Output: o_mid bf16 channel-last
// [b][vox][chunk-swizzled ci]  (chunk' = chunk ^ (vox&7)) - the layout conv's
// halo staging expects, making the final store a linear identity copy.
// ---------------------------------------------------------------------------
__global__ __launch_bounds__(512, 4) void attn_kernel(
    const float* __restrict__ x,
    const float* __restrict__ kbuf, const float* __restrict__ vbuf,
    const int* __restrict__ batch_nodes,
    const float* __restrict__ Wq, const float* __restrict__ bq,
    const float* __restrict__ Wo, const float* __restrict__ bo,
    __hip_bfloat16* __restrict__ omid) {
  __shared__ float sk[NATOM * C_];   // 16 KB
  __shared__ float sv[NATOM * C_];   // 16 KB
  __shared__ float xos[64 * C_];     // 16 KB: xs[c][vox] phase, then os phase

  const int b   = blockIdx.y;
  const int m0  = blockIdx.x * 64;
  const int tid = threadIdx.x;
  const int vox = tid & 63;
  const int w   = tid >> 6;
  const int h   = __builtin_amdgcn_readfirstlane(w);  // wave-uniform head
  const int lane = tid & 63;

  // stage x tile [c][vox] (4096 f32 = 16 KB) via global_load_lds.
  // Wave w stages chunks cidx = w*2+j (1024 B each): LDS base xos[cidx*256]
  // (wave-uniform), lane l covers channel cidx*4+(l>>4), voxels (l&15)*4..+4.
  #pragma unroll
  for (int j = 0; j < 2; ++j) {
    const int cidx = w * 2 + j;                  // 0..15
    const int c  = cidx * 4 + (lane >> 4);
    const int v4 = (lane & 15) * 4;
    const float* gsrc = x + (size_t)(b * C_ + c) * MVOX + m0 + v4;
    __builtin_amdgcn_global_load_lds((gas_u32*)gsrc,
                                     (las_u32*)&xos[cidx * 256], 16, 0, 0);
  }
  // stage K/V
  for (int i = tid; i < NATOM * C_; i += 512) {
    sk[i] = kbuf[b * NATOM * C_ + i];
    sv[i] = vbuf[b * NATOM * C_ + i];
  }
  __syncthreads();

  // ---- Q projection: thread computes q[8] for (vox, head h) ----
  float qa[8];
  #pragma unroll
  for (int j = 0; j < 8; ++j) qa[j] = bq[h * 8 + j];
  #pragma unroll 4
  for (int c4 = 0; c4 < 16; ++c4) {
    float xv[4];
    #pragma unroll
    for (int r = 0; r < 4; ++r) xv[r] = xos[(c4 * 4 + r) * C_ + vox];
    #pragma unroll
    for (int j = 0; j < 8; ++j) {
      const f32x4 wv = *(const f32x4*)&Wq[(h * 8 + j) * C_ + c4 * 4];  // scalar-cache
      qa[j] += xv[0] * wv.x + xv[1] * wv.y + xv[2] * wv.z + xv[3] * wv.w;
    }
  }
  const float scale = 0.3535533905932738f;
  #pragma unroll
  for (int j = 0; j < 8; ++j) qa[j] *= scale;
  __syncthreads();   // all xs reads done (xos becomes os)

  // ---- ragged attention, two 32-atom chunks, logits in registers ----
  const int nv = batch_nodes[b];
  float mrun = -1e30f, lsum = 0.f;
  float acc[8];
  #pragma unroll
  for (int d = 0; d < 8; ++d) acc[d] = 0.f;

  #pragma unroll
  for (int ch = 0; ch < 2; ++ch) {
    float l[32];
    float cmax = -1e30f;
    #pragma unroll
    for (int a = 0; a < 32; ++a) {
      const int atom = ch * 32 + a;
      const f32x4 k0 = *(const f32x4*)&sk[atom * C_ + h * 8];
      const f32x4 k1 = *(const f32x4*)&sk[atom * C_ + h * 8 + 4];
      float lg = qa[0]*k0.x + qa[1]*k0.y + qa[2]*k0.z + qa[3]*k0.w
               + qa[4]*k1.x + qa[5]*k1.y + qa[6]*k1.z + qa[7]*k1.w;
      lg = (atom < nv) ? lg : -1e30f;
      l[a] = lg;
      cmax = fmaxf(cmax, lg);
    }
    const float mnew = fmaxf(mrun, cmax);
    const float corr = __expf(mrun - mnew);
    lsum *= corr;
    #pragma unroll
    for (int d = 0; d < 8; ++d) acc[d] *= corr;
    #pragma unroll
    for (int a = 0; a < 32; ++a) {
      const int atom = ch * 32 + a;
      const float p = __expf(l[a] - mnew);
      lsum += p;
      const f32x4 v0 = *(const f32x4*)&sv[atom * C_ + h * 8];
      const f32x4 v1 = *(const f32x4*)&sv[atom * C_ + h * 8 + 4];
      acc[0] += p * v0.x;  acc[1] += p * v0.y;
      acc[2] += p * v0.z;  acc[3] += p * v0.w;
      acc[4] += p * v1.x;  acc[5] += p * v1.y;
      acc[6] += p * v1.z;  acc[7] += p * v1.w;
    }
    mrun = mnew;
  }
  const float inv = 1.f / lsum;

  // ---- write attention out to os (f32, XOR-swizzled 16B cols) ----
  float* os = xos;
  #pragma unroll
  for (int i = 0; i < 2; ++i) {
    const int c4 = h * 2 + i;
    f32x4 val;
    val.x = acc[i * 4 + 0] * inv; val.y = acc[i * 4 + 1] * inv;
    val.z = acc[i * 4 + 2] * inv; val.w = acc[i * 4 + 3] * inv;
    *(f32x4*)&os[vox * C_ + ((c4 ^ (vox & 15)) << 2)] = val;
  }
  __syncthreads();

  // ---- O projection + ReLU ----
  float oa[8];
  #pragma unroll
  for (int j = 0; j < 8; ++j) oa[j] = bo[h * 8 + j];
  #pragma unroll 4
  for (int c4 = 0; c4 < 16; ++c4) {
    const f32x4 ov = *(const f32x4*)&os[vox * C_ + ((c4 ^ (vox & 15)) << 2)];
    #pragma unroll
    for (int j = 0; j < 8; ++j) {
      const f32x4 wv = *(const f32x4*)&Wo[(h * 8 + j) * C_ + c4 * 4];  // scalar-cache
      oa[j] += ov.x * wv.x + ov.y * wv.y + ov.z * wv.z + ov.w * wv.w;
    }
  }
  __syncthreads();   // all os reads done before bf16 alias-overwrite

  // ---- pack bf16 into os alias at chunk' = h ^ (vox&7) ----
  __hip_bfloat16* osb = (__hip_bfloat16*)os;
  ushort8 pk;
  #pragma unroll
  for (int j = 0; j < 8; ++j) {
    __hip_bfloat16 hb = __float2bfloat16(fmaxf(oa[j], 0.f));
    pk[j] = *(unsigned short*)&hb;
  }
  *(ushort8*)&osb[vox * C_ + ((h ^ (vox & 7)) << 3)] = pk;
  __syncthreads();

  // ---- linear identity copy: osb already holds the swizzled layout ----
  *(ushort8*)(omid + (size_t)(b * MVOX + m0) * C_ + tid * 8) =
      *(const ushort8*)&osb[tid * 8];
}

// ---------------------------------------------------------------------------
// Kernel 3: conv3d 3x3x3 circular, implicit-GEMM MFMA.
//   omid: bf16 channel-last, chunk-swizzled (chunk' = chunk ^ (vox&7))
//   Wt  : bf16 [tap][co][chunk^(co&7)]  (pre-swizzled)
// Halo (64 KB) + per-tap weights (2 x 8 KB ring) staged via global_load_lds.
// 2-phase pipeline: stage tap t+1, compute tap t, barrier.
// ---------------------------------------------------------------------------
__global__ __launch_bounds__(256, 2) void conv_kernel(
    const __hip_bfloat16* __restrict__ omid,
    const __hip_bfloat16* __restrict__ Wt,
    const float* __restrict__ bc,
    const float* __restrict__ xin,
    float* __restrict__ out) {
  __shared__ __hip_bfloat16 halo[512 * 64];   // 64 KB
  __shared__ __hip_bfloat16 wbuf[2 * 4096];   // 16 KB ring

  const int b    = blockIdx.y;
  const int x0   = (blockIdx.x >> 4) * 2;
  const int y0   = (blockIdx.x & 15) * 2;
  const int tid  = threadIdx.x;
  const int lane = tid & 63;
  const int w    = tid >> 6;

  // --- halo staging: 64 chunks x 1KB, wave w stages chunks [w*16, w*16+16) ---
  {
    const __hip_bfloat16* src = omid + (size_t)b * MVOX * C_;
    #pragma unroll
    for (int n = 0; n < 16; ++n) {
      const int chunk = w * 16 + n;
      const int li = chunk >> 2;                 // halo line 0..15
      const int zb = (chunk & 3) * 8;
      const int gx = (x0 - 1 + (li >> 2)) & 31;
      const int gy = (y0 - 1 + (li & 3)) & 31;
      const __hip_bfloat16* gsrc = src + (size_t)(gx * 1024 + gy * 32 + zb) * C_ + lane * 8;
      __builtin_amdgcn_global_load_lds((gas_u32*)gsrc,
                                       (las_u32*)&halo[chunk * 512], 16, 0, 0);
    }
  }
  // --- stage weights for tap 0 ---
  {
    const __hip_bfloat16* gsrc = Wt + w * 1024 + lane * 8;
    __builtin_amdgcn_global_load_lds((gas_u32*)gsrc,
                                     (las_u32*)&wbuf[w * 1024], 16, 0, 0);
    __builtin_amdgcn_global_load_lds((gas_u32*)(gsrc + 512),
                                     (las_u32*)&wbuf[w * 1024 + 512], 16, 0, 0);
  }
  __syncthreads();

  const int xl = w >> 1, yl = w & 1;
  const int row = lane & 15, quad = lane >> 4;

  f32x4 acc[4][2];
  #pragma unroll
  for (int cf = 0; cf < 4; ++cf)
    #pragma unroll
    for (int f = 0; f < 2; ++f)
      #pragma unroll
      for (int r = 0; r < 4; ++r) acc[cf][f][r] = 0.f;

  #pragma unroll
  for (int t = 0; t < 27; ++t) {
    const int buf = t & 1;
    // stage tap t+1 into the other buffer (hidden under compute)
    if (t < 26) {
      const __hip_bfloat16* gsrc = Wt + (t + 1) * 4096 + w * 1024 + lane * 8;
      __builtin_amdgcn_global_load_lds((gas_u32*)gsrc,
                                       (las_u32*)&wbuf[(buf ^ 1) * 4096 + w * 1024], 16, 0, 0);
      __builtin_amdgcn_global_load_lds((gas_u32*)(gsrc + 512),
                                       (las_u32*)&wbuf[(buf ^ 1) * 4096 + w * 1024 + 512], 16, 0, 0);
    }
    const int dxy = t / 3, dz = t % 3;
    const int dx = dxy / 3, dy = dxy % 3;
    const int hline = (xl + dx) * 4 + (yl + dy);

    bf16x8 bfr[2][2];
    #pragma unroll
    for (int f = 0; f < 2; ++f) {
      const int zs = (f * 16 + row + dz - 1) & 31;
      const int sw = zs & 7;
      #pragma unroll
      for (int kh = 0; kh < 2; ++kh) {
        const int a16 = (hline * 32 + zs) * 8 + ((kh * 4 + quad) ^ sw);
        bfr[f][kh] = *(const bf16x8*)&halo[a16 * 8];
      }
    }
    #pragma unroll
    for (int kh = 0; kh < 2; ++kh) {
      #pragma unroll
      for (int cf = 0; cf < 4; ++cf) {
        const int a16w = ((cf * 16 + row) << 3) + ((kh * 4 + quad) ^ (row & 7));
        const bf16x8 afr = *(const bf16x8*)&wbuf[buf * 4096 + a16w * 8];
        acc[cf][0] = __builtin_amdgcn_mfma_f32_16x16x32_bf16(afr, bfr[0][kh], acc[cf][0], 0, 0, 0);
        acc[cf][1] = __builtin_amdgcn_mfma_f32_16x16x32_bf16(afr, bfr[1][kh], acc[cf][1], 0, 0, 0);
      }
    }
    if (t < 26) __syncthreads();
  }

  // --- epilogue: relu(acc+bias) + residual, f32 [b][co][vox] ---
  const int gx = x0 + xl, gy = y0 + yl;
  #pragma unroll
  for (int cf = 0; cf < 4; ++cf)
    #pragma unroll
    for (int f = 0; f < 2; ++f) {
      const int z = f * 16 + row;
      #pragma unroll
      for (int r = 0; r < 4; ++r) {
        const int co = cf * 16 + quad * 4 + r;
        const size_t idx = ((size_t)(b * C_ + co)) * MVOX + gx * 1024 + gy * 32 + z;
        out[idx] = fmaxf(acc[cf][f][r] + bc[co], 0.f) + xin[idx];
      }
    }
}

// ---------------------------------------------------------------------------
extern "C" void kernel_launch(void* const* d_in, const int* in_sizes, int n_in,
                              void* d_out, int out_size, void* d_ws, size_t ws_size,
                              hipStream_t stream) {
  const float* x   = (const float*)d_in[0];
  const float* mol = (const float*)d_in[1];
  const int*   bn  = (const int*)  d_in[2];
  const float* Wq  = (const float*)d_in[3];
  const float* bq  = (const float*)d_in[4];
  const float* Wk  = (const float*)d_in[5];
  const float* bk  = (const float*)d_in[6];
  const float* Wv  = (const float*)d_in[7];
  const float* bv  = (const float*)d_in[8];
  const float* Wo  = (const float*)d_in[9];
  const float* bo  = (const float*)d_in[10];
  const float* Wc  = (const float*)d_in[11];
  const float* bc  = (const float*)d_in[12];
  float* out = (float*)d_out;

  char* ws = (char*)d_ws;
  __hip_bfloat16* omid = (__hip_bfloat16*)ws;                        // 16,777,216 B
  float* kbuf = (float*)(ws + 16777216);
  float* vbuf = kbuf + B_ * NATOM * C_;
  __hip_bfloat16* Wt = (__hip_bfloat16*)(ws + 16777216 + 2 * 65536);

  wprep_kernel<<<dim3(432), 256, 0, stream>>>(Wc, Wt);
  kv_kernel<<<dim3(B_, 2), 256, 0, stream>>>(mol, Wk, bk, Wv, bv, kbuf, vbuf);
  attn_kernel<<<dim3(MVOX / 64, B_), 512, 0, stream>>>(x, kbuf, vbuf, bn, Wq, bq, Wo, bo, omid);
  conv_kernel<<<dim3(256, B_), 256, 0, stream>>>(omid, Wt, bc, x, out);
}